// Round 1
// baseline (261.722 us; speedup 1.0000x reference)
//
#include <hip/hip_runtime.h>
#include <hip/hip_bf16.h>

typedef unsigned short u16;
typedef unsigned int u32;
typedef __attribute__((ext_vector_type(8))) short bf16x8;
typedef __attribute__((ext_vector_type(4))) float f32x4;

#define MFMA(a, b, c) __builtin_amdgcn_mfma_f32_16x16x32_bf16(a, b, c, 0, 0, 0)

__device__ __forceinline__ u16 f2b(float f) {
    u32 x = __float_as_uint(f);
    return (u16)((x + 0x7fffu + ((x >> 16) & 1u)) >> 16);  // RNE, no NaN in data
}
__device__ __forceinline__ bf16x8 ldb8(const u16* p) {
    return *reinterpret_cast<const bf16x8*>(p);
}

// ---- convert weights to bf16 (w_qkv 384x256, w_out 256x128, same layouts) ----
__global__ void k_convw(const float* wq, const float* wo, u16* wqb, u16* wob) {
    int i4 = (blockIdx.x * 256 + threadIdx.x) * 4;
    const float* s;
    u16* d;
    if (i4 < 384 * 256) { s = wq + i4; d = wqb + i4; }
    else { int j = i4 - 384 * 256; s = wo + j; d = wob + j; }
    float4 v = *(const float4*)s;
    u16 o[4] = {f2b(v.x), f2b(v.y), f2b(v.z), f2b(v.w)};
    *(uint2*)d = *(uint2*)o;
}

// ---- generic 32x32-tiled transpose fp32[R][C] -> bf16[C][R], optional per-row scale ----
__global__ void k_trans(const float* __restrict__ src, u16* __restrict__ dst,
                        const float* __restrict__ scale,
                        int R, int C, int H, long sbB, long shB, int scb, int sch) {
    __shared__ float ld[32][33];
    int p = blockIdx.z;
    int b = p / H, h = p - b * H;
    const float* s = src + (long)b * sbB + (long)h * shB;
    u16* d = dst + (long)p * (long)R * (long)C;
    const float* sc = scale ? (scale + b * scb + h * sch) : nullptr;
    int c0 = blockIdx.x * 32, r0 = blockIdx.y * 32;
    int tx = threadIdx.x, ty = threadIdx.y;
#pragma unroll
    for (int i = 0; i < 4; i++) {
        int r = r0 + ty + 8 * i;
        float f = s[(long)r * C + c0 + tx];
        if (sc) f *= sc[r];
        ld[ty + 8 * i][tx] = f;
    }
    __syncthreads();
#pragma unroll
    for (int i = 0; i < 4; i++) {
        int c = c0 + ty + 8 * i;
        d[(long)c * R + r0 + tx] = f2b(ld[tx][ty + 8 * i]);
    }
}

// ---- GEMM1: qkv[b][384][4096] f32 = Wqkv(384x256) x X_t  (per-wave 16o x 64n) ----
__global__ __launch_bounds__(256) void k_gemm1(const u16* __restrict__ wqb,
                                               const u16* __restrict__ xt,
                                               float* __restrict__ qkv) {
    int lane = threadIdx.x & 63;
    int wid = blockIdx.x * 4 + (threadIdx.x >> 6);   // 6144 waves
    int b = wid / 1536;
    int rem = wid - b * 1536;
    int ot = rem >> 6, ng = rem & 63;
    int o0 = ot * 16, n0 = ng * 64;
    int lr = lane & 15, lg = lane >> 4;
    const u16* A = wqb + (o0 + lr) * 256 + lg * 8;
    const u16* B = xt + ((long)b * 4096 + n0 + lr) * 256 + lg * 8;
    f32x4 z = {0.f, 0.f, 0.f, 0.f};
    f32x4 acc[4] = {z, z, z, z};
#pragma unroll
    for (int kk = 0; kk < 8; kk++) {
        bf16x8 af = ldb8(A + kk * 32);
#pragma unroll
        for (int c = 0; c < 4; c++) {
            bf16x8 bb = ldb8(B + c * 16 * 256 + kk * 32);
            acc[c] = MFMA(af, bb, acc[c]);
        }
    }
    float* out = qkv + (long)b * 1572864 + (long)(o0 + lg * 4) * 4096 + n0 + lr;
#pragma unroll
    for (int c = 0; c < 4; c++)
#pragma unroll
        for (int r = 0; r < 4; r++)
            out[r * 4096 + c * 16] = acc[c][r];
}

// ---- row L2-norms of q,k parts: inv[b*256+o] = 1/max(||qkv[b][o][:]||, 1e-12) ----
__global__ void k_norm(const float* __restrict__ qkv, float* __restrict__ inv) {
    int row = blockIdx.x;               // 0..1023
    int b = row >> 8, o = row & 255;
    const float* p = qkv + (long)b * 1572864 + (long)o * 4096;
    float ss = 0.f;
    int t = threadIdx.x;
    for (int n = t * 4; n < 4096; n += 1024) {
        float4 v = *(const float4*)(p + n);
        ss += v.x * v.x + v.y * v.y + v.z * v.z + v.w * v.w;
    }
#pragma unroll
    for (int off = 1; off < 64; off <<= 1) ss += __shfl_xor(ss, off);
    __shared__ float red[4];
    if ((t & 63) == 0) red[t >> 6] = ss;
    __syncthreads();
    if (t == 0) {
        float s = red[0] + red[1] + red[2] + red[3];
        inv[row] = 1.0f / fmaxf(sqrtf(s), 1e-12f);
    }
}

// ---- v part -> bf16, same [b][128][4096] layout ----
__global__ void k_convv(const float* __restrict__ qkv, u16* __restrict__ vb) {
    long idx4 = ((long)blockIdx.x * 256 + threadIdx.x) * 4;
    long b = idx4 >> 19;
    long rem = idx4 & 524287;
    float4 v = *(const float4*)(qkv + b * 1572864 + 1048576 + rem);
    u16 o[4] = {f2b(v.x), f2b(v.y), f2b(v.z), f2b(v.w)};
    *(uint2*)(vb + idx4) = *(uint2*)o;
}

// ---- flash attention: qt/kt [bh][4096][32] bf16, vb [bh][32][4096] bf16,
// ---- ot [b][4096][128] bf16.  No max-subtraction (|sim|<0.3 guaranteed).
__global__ __launch_bounds__(256) void k_attn(const u16* __restrict__ qt,
                                              const u16* __restrict__ kt,
                                              const u16* __restrict__ vb,
                                              u16* __restrict__ ot) {
    __shared__ __align__(16) u16 pbuf[4][2][16 * 40];   // per-wave,per-tau P tile, pitch 40
    __shared__ float lbuf[4][2][16];
    int wv = threadIdx.x >> 6, lane = threadIdx.x & 63;
    int bid = blockIdx.x;
    int swz = (bid & 7) * 64 + (bid >> 3);     // XCD swizzle, 512 % 8 == 0 -> bijective
    int bh = swz >> 5, iblk = swz & 31;
    int lr = lane & 15, lg = lane >> 4;
    long base = (long)bh * 131072;             // 4096*32 elements per (b,h)
    int i0 = iblk * 128 + wv * 32;

    bf16x8 qa[2];
    qa[0] = ldb8(qt + base + (long)(i0 + lr) * 32 + lg * 8);
    qa[1] = ldb8(qt + base + (long)(i0 + 16 + lr) * 32 + lg * 8);

    f32x4 z = {0.f, 0.f, 0.f, 0.f};
    f32x4 acc[2][2] = {{z, z}, {z, z}};
    float lac[2][4] = {{0.f, 0.f, 0.f, 0.f}, {0.f, 0.f, 0.f, 0.f}};

    const u16* Kp = kt + base + lr * 32 + lg * 8;
    const u16* Vp = vb + base + (long)lr * 4096 + lg * 8;
    const float RC = 14.426950408889634f;      // SCALE * log2(e)

    for (int j0 = 0; j0 < 4096; j0 += 32) {
        bf16x8 kb0 = ldb8(Kp + j0 * 32);
        bf16x8 kb1 = ldb8(Kp + j0 * 32 + 512);
        bf16x8 va0 = ldb8(Vp + j0);
        bf16x8 va1 = ldb8(Vp + 65536 + j0);
#pragma unroll
        for (int tau = 0; tau < 2; tau++) {
            f32x4 s0 = MFMA(qa[tau], kb0, z);
            f32x4 s1 = MFMA(qa[tau], kb1, z);
            u16* pb = &pbuf[wv][tau][0];
#pragma unroll
            for (int r = 0; r < 4; r++) {
                float p0 = exp2f(s0[r] * RC);
                float p1 = exp2f(s1[r] * RC);
                lac[tau][r] += p0 + p1;
                pb[(lg * 4 + r) * 40 + lr] = f2b(p0);
                pb[(lg * 4 + r) * 40 + lr + 16] = f2b(p1);
            }
            asm volatile("s_waitcnt lgkmcnt(0)" ::: "memory");
            bf16x8 pa = ldb8(pb + lr * 40 + lg * 8);   // A-frag of P == B-frag of P^T
            acc[tau][0] = MFMA(va0, pa, acc[tau][0]);
            acc[tau][1] = MFMA(va1, pa, acc[tau][1]);
        }
    }

    int b = bh >> 2, h = bh & 3;
#pragma unroll
    for (int tau = 0; tau < 2; tau++) {
        float l0 = lac[tau][0], l1 = lac[tau][1], l2 = lac[tau][2], l3 = lac[tau][3];
#pragma unroll
        for (int off = 1; off < 16; off <<= 1) {
            l0 += __shfl_xor(l0, off);
            l1 += __shfl_xor(l1, off);
            l2 += __shfl_xor(l2, off);
            l3 += __shfl_xor(l3, off);
        }
        if (lr == 0) {
            lbuf[wv][tau][lg * 4 + 0] = l0;
            lbuf[wv][tau][lg * 4 + 1] = l1;
            lbuf[wv][tau][lg * 4 + 2] = l2;
            lbuf[wv][tau][lg * 4 + 3] = l3;
        }
        __syncthreads();
        float linv = 1.0f / lbuf[wv][tau][lr];
        u16* pb = &pbuf[wv][tau][0];
#pragma unroll
        for (int t = 0; t < 2; t++)
#pragma unroll
            for (int r = 0; r < 4; r++)
                pb[lr * 40 + lg * 4 + r + 16 * t] = f2b(acc[tau][t][r] * linv);
        __syncthreads();
        int orow = lane >> 2, och = lane & 3;
        bf16x8 ov = ldb8(pb + orow * 40 + och * 8);
        long oaddr = ((long)(b * 4096 + i0 + tau * 16 + orow)) * 128 + h * 32 + och * 8;
        *reinterpret_cast<bf16x8*>(ot + oaddr) = ov;
    }
}

// ---- GEMM2: y[b][256][4096] f32 = Wout(256x128) x O_t + b_out ----
__global__ __launch_bounds__(256) void k_gemm2(const u16* __restrict__ wob,
                                               const u16* __restrict__ ot,
                                               const float* __restrict__ bout,
                                               float* __restrict__ y) {
    int lane = threadIdx.x & 63;
    int wid = blockIdx.x * 4 + (threadIdx.x >> 6);   // 4096 waves
    int b = wid >> 10;
    int rem = wid & 1023;
    int otl = rem >> 6, ng = rem & 63;
    int o0 = otl * 16, n0 = ng * 64;
    int lr = lane & 15, lg = lane >> 4;
    const u16* A = wob + (o0 + lr) * 128 + lg * 8;
    const u16* B = ot + ((long)b * 4096 + n0 + lr) * 128 + lg * 8;
    f32x4 z = {0.f, 0.f, 0.f, 0.f};
    f32x4 acc[4] = {z, z, z, z};
#pragma unroll
    for (int kk = 0; kk < 4; kk++) {
        bf16x8 af = ldb8(A + kk * 32);
#pragma unroll
        for (int c = 0; c < 4; c++) {
            bf16x8 bb = ldb8(B + c * 16 * 128 + kk * 32);
            acc[c] = MFMA(af, bb, acc[c]);
        }
    }
    float bo[4];
#pragma unroll
    for (int r = 0; r < 4; r++) bo[r] = bout[o0 + lg * 4 + r];
    float* out = y + (long)b * 1048576 + (long)(o0 + lg * 4) * 4096 + n0 + lr;
#pragma unroll
    for (int c = 0; c < 4; c++)
#pragma unroll
        for (int r = 0; r < 4; r++)
            out[r * 4096 + c * 16] = acc[c][r] + bo[r];
}

extern "C" void kernel_launch(void* const* d_in, const int* in_sizes, int n_in,
                              void* d_out, int out_size, void* d_ws, size_t ws_size,
                              hipStream_t stream) {
    const float* x    = (const float*)d_in[0];
    const float* wqkv = (const float*)d_in[1];
    const float* wout = (const float*)d_in[2];
    const float* bout = (const float*)d_in[3];
    float* y = (float*)d_out;
    char* ws = (char*)d_ws;

    u16*   wqb = (u16*)(ws);                 //   196,608 B
    u16*   wob = (u16*)(ws + 196608);        //    65,536
    u16*   xt  = (u16*)(ws + 262144);        // 8,388,608
    float* qkv = (float*)(ws + 8650752);     // 25,165,824
    float* inv = (float*)(ws + 33816576);    //     4,096
    u16*   qt  = (u16*)(ws + 33820672);      // 4,194,304
    u16*   kt  = (u16*)(ws + 38014976);      // 4,194,304
    u16*   vb  = (u16*)(ws + 42209280);      // 4,194,304
    u16*   ot  = (u16*)(ws + 46403584);      // 4,194,304  -> total 50,597,888 B

    k_convw<<<128, 256, 0, stream>>>(wqkv, wout, wqb, wob);
    k_trans<<<dim3(128, 8, 4), dim3(32, 8), 0, stream>>>(
        x, xt, nullptr, 256, 4096, 1, 1048576L, 0L, 0, 0);
    k_gemm1<<<1536, 256, 0, stream>>>(wqb, xt, qkv);
    k_norm<<<1024, 256, 0, stream>>>(qkv, inv);
    k_trans<<<dim3(128, 1, 16), dim3(32, 8), 0, stream>>>(
        qkv, qt, inv, 32, 4096, 4, 1572864L, 131072L, 256, 32);
    k_trans<<<dim3(128, 1, 16), dim3(32, 8), 0, stream>>>(
        qkv + 524288, kt, inv + 128, 32, 4096, 4, 1572864L, 131072L, 256, 32);
    k_convv<<<2048, 256, 0, stream>>>(qkv, vb);
    k_attn<<<512, 256, 0, stream>>>(qt, kt, vb, ot);
    k_gemm2<<<1024, 256, 0, stream>>>(wob, ot, bout, y);
}

// Round 3
// 219.784 us; speedup vs baseline: 1.1908x; 1.1908x over previous
//
#include <hip/hip_runtime.h>
#include <hip/hip_bf16.h>

typedef unsigned short u16;
typedef unsigned int u32;
typedef __attribute__((ext_vector_type(8))) short bf16x8;
typedef __attribute__((ext_vector_type(4))) float f32x4;

#define MFMA(a, b, c) __builtin_amdgcn_mfma_f32_16x16x32_bf16(a, b, c, 0, 0, 0)

__device__ __forceinline__ u16 f2b(float f) {
    u32 x = __float_as_uint(f);
    return (u16)((x + 0x7fffu + ((x >> 16) & 1u)) >> 16);  // RNE, no NaN in data
}
__device__ __forceinline__ bf16x8 ldb8(const u16* p) {
    return *reinterpret_cast<const bf16x8*>(p);
}
__device__ __forceinline__ int cvt_pk(float lo, float hi) {
    int r;
    asm("v_cvt_pk_bf16_f32 %0, %1, %2" : "=v"(r) : "v"(lo), "v"(hi));
    return r;
}

// ---- convert weights to bf16 (w_qkv 384x256, w_out 256x128, same layouts) ----
__global__ void k_convw(const float* wq, const float* wo, u16* wqb, u16* wob) {
    int i4 = (blockIdx.x * 256 + threadIdx.x) * 4;
    const float* s;
    u16* d;
    if (i4 < 384 * 256) { s = wq + i4; d = wqb + i4; }
    else { int j = i4 - 384 * 256; s = wo + j; d = wob + j; }
    float4 v = *(const float4*)s;
    u16 o[4] = {f2b(v.x), f2b(v.y), f2b(v.z), f2b(v.w)};
    *(uint2*)d = *(uint2*)o;
}

// ---- generic 32x32-tiled transpose fp32[R][C] -> bf16[C][R], optional per-row scale ----
__global__ void k_trans(const float* __restrict__ src, u16* __restrict__ dst,
                        const float* __restrict__ scale,
                        int R, int C, int H, long sbB, long shB, int scb, int sch) {
    __shared__ float ld[32][33];
    int p = blockIdx.z;
    int b = p / H, h = p - b * H;
    const float* s = src + (long)b * sbB + (long)h * shB;
    u16* d = dst + (long)p * (long)R * (long)C;
    const float* sc = scale ? (scale + b * scb + h * sch) : nullptr;
    int c0 = blockIdx.x * 32, r0 = blockIdx.y * 32;
    int tx = threadIdx.x, ty = threadIdx.y;
#pragma unroll
    for (int i = 0; i < 4; i++) {
        int r = r0 + ty + 8 * i;
        float f = s[(long)r * C + c0 + tx];
        if (sc) f *= sc[r];
        ld[ty + 8 * i][tx] = f;
    }
    __syncthreads();
#pragma unroll
    for (int i = 0; i < 4; i++) {
        int c = c0 + ty + 8 * i;
        d[(long)c * R + r0 + tx] = f2b(ld[tx][ty + 8 * i]);
    }
}

// ---- GEMM1: Wqkv(384x256) x X_t. q,k rows (o<256) -> qkv f32 [b][256][4096];
// ----        v rows (o>=256) -> vb bf16 [b][128][4096] directly.
__global__ __launch_bounds__(256) void k_gemm1(const u16* __restrict__ wqb,
                                               const u16* __restrict__ xt,
                                               float* __restrict__ qkv,
                                               u16* __restrict__ vb) {
    int lane = threadIdx.x & 63;
    int wid = blockIdx.x * 4 + (threadIdx.x >> 6);   // 6144 waves
    int b = wid / 1536;
    int rem = wid - b * 1536;
    int ot = rem >> 6, ng = rem & 63;
    int o0 = ot * 16, n0 = ng * 64;
    int lr = lane & 15, lg = lane >> 4;
    const u16* A = wqb + (o0 + lr) * 256 + lg * 8;
    const u16* B = xt + ((long)b * 4096 + n0 + lr) * 256 + lg * 8;
    f32x4 z = {0.f, 0.f, 0.f, 0.f};
    f32x4 acc[4] = {z, z, z, z};
#pragma unroll
    for (int kk = 0; kk < 8; kk++) {
        bf16x8 af = ldb8(A + kk * 32);
#pragma unroll
        for (int c = 0; c < 4; c++) {
            bf16x8 bb = ldb8(B + c * 16 * 256 + kk * 32);
            acc[c] = MFMA(af, bb, acc[c]);
        }
    }
    if (o0 < 256) {
        float* out = qkv + (long)b * 1048576 + (long)(o0 + lg * 4) * 4096 + n0 + lr;
#pragma unroll
        for (int c = 0; c < 4; c++)
#pragma unroll
            for (int r = 0; r < 4; r++)
                out[r * 4096 + c * 16] = acc[c][r];
    } else {
        u16* out = vb + (long)b * 524288 + (long)(o0 - 256 + lg * 4) * 4096 + n0 + lr;
#pragma unroll
        for (int c = 0; c < 4; c++)
#pragma unroll
            for (int r = 0; r < 4; r++)
                out[r * 4096 + c * 16] = f2b(acc[c][r]);
    }
}

// ---- row L2-norms of q,k: inv[b*256+o] = mult / max(||row||, 1e-12)
// ---- mult folds SCALE*log2(e) into q so the attn loop feeds exp2 directly.
__global__ void k_norm(const float* __restrict__ qkv, float* __restrict__ inv) {
    int row = blockIdx.x;               // 0..1023
    int b = row >> 8, o = row & 255;
    const float* p = qkv + (long)b * 1048576 + (long)o * 4096;
    float ss = 0.f;
    int t = threadIdx.x;
    for (int n = t * 4; n < 4096; n += 1024) {
        float4 v = *(const float4*)(p + n);
        ss += v.x * v.x + v.y * v.y + v.z * v.z + v.w * v.w;
    }
#pragma unroll
    for (int off = 1; off < 64; off <<= 1) ss += __shfl_xor(ss, off);
    __shared__ float red[4];
    if ((t & 63) == 0) red[t >> 6] = ss;
    __syncthreads();
    if (t == 0) {
        float s = red[0] + red[1] + red[2] + red[3];
        float mult = (o < 128) ? 14.426950408889634f : 1.0f;   // 10*log2(e) for q
        inv[row] = mult / fmaxf(sqrtf(s), 1e-12f);
    }
}

// ---- flash attention, P fully in-register via swapped QK^T + permlane swaps.
// ---- qt/kt [bh][4096][32] bf16 (q pre-scaled by 10*log2e), vb [b][128][4096],
// ---- ot [b][4096][128].  No max-subtraction needed (values bounded, bf16-safe).
__global__ __launch_bounds__(256) void k_attn(const u16* __restrict__ qt,
                                              const u16* __restrict__ kt,
                                              const u16* __restrict__ vb,
                                              u16* __restrict__ ot) {
    int wv = threadIdx.x >> 6, lane = threadIdx.x & 63;
    int bid = blockIdx.x;
    int swz = (bid & 7) * 64 + (bid >> 3);     // XCD swizzle, 512 % 8 == 0 -> bijective
    int bh = swz >> 5, iblk = swz & 31;
    int lr = lane & 15, lg = lane >> 4;
    long base = (long)bh * 131072;             // 4096*32 elements per (b,h)
    int i0 = iblk * 128 + wv * 32;

    bf16x8 qa[2];
    qa[0] = ldb8(qt + base + (long)(i0 + lr) * 32 + lg * 8);
    qa[1] = ldb8(qt + base + (long)(i0 + 16 + lr) * 32 + lg * 8);

    f32x4 z = {0.f, 0.f, 0.f, 0.f};
    f32x4 acc[2][2] = {{z, z}, {z, z}};
    float lsum[2] = {0.f, 0.f};

    const u16* Kp = kt + base + lr * 32 + lg * 8;
    const u16* Vp = vb + base + (long)lr * 4096 + lg * 8;

    for (int j0 = 0; j0 < 4096; j0 += 32) {
        bf16x8 kb0 = ldb8(Kp + j0 * 32);
        bf16x8 kb1 = ldb8(Kp + j0 * 32 + 512);
        bf16x8 va0 = ldb8(Vp + j0);
        bf16x8 va1 = ldb8(Vp + 65536 + j0);
#pragma unroll
        for (int tau = 0; tau < 2; tau++) {
            // Swapped QK^T: lane holds S^T[j = 4*lg + r][i = lr] per 16-j tile.
            f32x4 s0 = MFMA(kb0, qa[tau], z);
            f32x4 s1 = MFMA(kb1, qa[tau], z);
            float p0[4], p1[4];
#pragma unroll
            for (int r = 0; r < 4; r++) {
                p0[r] = __builtin_amdgcn_exp2f(s0[r]);
                p1[r] = __builtin_amdgcn_exp2f(s1[r]);
            }
            lsum[tau] += ((p0[0] + p0[1]) + (p0[2] + p0[3]))
                       + ((p1[0] + p1[1]) + (p1[2] + p1[3]));
            // Pack to bf16 pairs: m(x) := pair (P[j=2x][i=lr], P[j=2x+1][i=lr]).
            // Lane lg holds a0=m(2lg) a1=m(2lg+1) b0=m(8+2lg) b1=m(8+2lg+1);
            // PV B-frag needs t_e = m(4lg+e), e=0..3.
            int a0 = cvt_pk(p0[0], p0[1]);
            int a1 = cvt_pk(p0[2], p0[3]);
            int b0 = cvt_pk(p1[0], p1[1]);
            int b1 = cvt_pk(p1[2], p1[3]);
            // swap32: new_a = {a_lo, b_lo}, new_b = {a_hi, b_hi} (lane halves)
            {
                auto r0_ = __builtin_amdgcn_permlane32_swap(a0, b0, false, false);
                a0 = r0_[0]; b0 = r0_[1];
                auto r1_ = __builtin_amdgcn_permlane32_swap(a1, b1, false, false);
                a1 = r1_[0]; b1 = r1_[1];
                // swap16: exchanges dst 16-lane groups 1,3 with src groups 0,2
                auto r2_ = __builtin_amdgcn_permlane16_swap(a0, b0, false, false);
                a0 = r2_[0]; b0 = r2_[1];
                auto r3_ = __builtin_amdgcn_permlane16_swap(a1, b1, false, false);
                a1 = r3_[0]; b1 = r3_[1];
            }
            union { int w[4]; bf16x8 v; } pu;
            pu.w[0] = a0; pu.w[1] = a1; pu.w[2] = b0; pu.w[3] = b1;
            acc[tau][0] = MFMA(va0, pu.v, acc[tau][0]);
            acc[tau][1] = MFMA(va1, pu.v, acc[tau][1]);
        }
    }

    int b = bh >> 2, h = bh & 3;
#pragma unroll
    for (int tau = 0; tau < 2; tau++) {
        float l = lsum[tau];
        l += __shfl_xor(l, 16);
        l += __shfl_xor(l, 32);
        float linv = 1.0f / l;
        u16* op = ot + ((long)(b * 4096 + i0 + tau * 16 + lr)) * 128 + h * 32;
#pragma unroll
        for (int t = 0; t < 2; t++)
#pragma unroll
            for (int s = 0; s < 2; s++) {
                int w = cvt_pk(acc[tau][t][2 * s] * linv, acc[tau][t][2 * s + 1] * linv);
                *(int*)(op + 16 * t + 4 * lg + 2 * s) = w;
            }
    }
}

// ---- GEMM2: y[b][256][4096] f32 = Wout(256x128) x O_t + b_out ----
__global__ __launch_bounds__(256) void k_gemm2(const u16* __restrict__ wob,
                                               const u16* __restrict__ ot,
                                               const float* __restrict__ bout,
                                               float* __restrict__ y) {
    int lane = threadIdx.x & 63;
    int wid = blockIdx.x * 4 + (threadIdx.x >> 6);   // 4096 waves
    int b = wid >> 10;
    int rem = wid & 1023;
    int otl = rem >> 6, ng = rem & 63;
    int o0 = otl * 16, n0 = ng * 64;
    int lr = lane & 15, lg = lane >> 4;
    const u16* A = wob + (o0 + lr) * 128 + lg * 8;
    const u16* B = ot + ((long)b * 4096 + n0 + lr) * 128 + lg * 8;
    f32x4 z = {0.f, 0.f, 0.f, 0.f};
    f32x4 acc[4] = {z, z, z, z};
#pragma unroll
    for (int kk = 0; kk < 4; kk++) {
        bf16x8 af = ldb8(A + kk * 32);
#pragma unroll
        for (int c = 0; c < 4; c++) {
            bf16x8 bb = ldb8(B + c * 16 * 128 + kk * 32);
            acc[c] = MFMA(af, bb, acc[c]);
        }
    }
    float bo[4];
#pragma unroll
    for (int r = 0; r < 4; r++) bo[r] = bout[o0 + lg * 4 + r];
    float* out = y + (long)b * 1048576 + (long)(o0 + lg * 4) * 4096 + n0 + lr;
#pragma unroll
    for (int c = 0; c < 4; c++)
#pragma unroll
        for (int r = 0; r < 4; r++)
            out[r * 4096 + c * 16] = acc[c][r] + bo[r];
}

extern "C" void kernel_launch(void* const* d_in, const int* in_sizes, int n_in,
                              void* d_out, int out_size, void* d_ws, size_t ws_size,
                              hipStream_t stream) {
    const float* x    = (const float*)d_in[0];
    const float* wqkv = (const float*)d_in[1];
    const float* wout = (const float*)d_in[2];
    const float* bout = (const float*)d_in[3];
    float* y = (float*)d_out;
    char* ws = (char*)d_ws;

    u16*   wqb = (u16*)(ws);                 //   196,608 B
    u16*   wob = (u16*)(ws + 196608);        //    65,536
    u16*   xt  = (u16*)(ws + 262144);        // 8,388,608
    float* qkv = (float*)(ws + 8650752);     // 16,777,216  (q,k only)
    float* inv = (float*)(ws + 25427968);    //     4,096
    u16*   qt  = (u16*)(ws + 25432064);      // 4,194,304
    u16*   kt  = (u16*)(ws + 29626368);      // 4,194,304
    u16*   vb  = (u16*)(ws + 33820672);      // 4,194,304
    u16*   ot  = (u16*)(ws + 38014976);      // 4,194,304  -> total 42,209,280 B

    k_convw<<<128, 256, 0, stream>>>(wqkv, wout, wqb, wob);
    k_trans<<<dim3(128, 8, 4), dim3(32, 8), 0, stream>>>(
        x, xt, nullptr, 256, 4096, 1, 1048576L, 0L, 0, 0);
    k_gemm1<<<1536, 256, 0, stream>>>(wqb, xt, qkv, vb);
    k_norm<<<1024, 256, 0, stream>>>(qkv, inv);
    k_trans<<<dim3(128, 1, 16), dim3(32, 8), 0, stream>>>(
        qkv, qt, inv, 32, 4096, 4, 1048576L, 131072L, 256, 32);
    k_trans<<<dim3(128, 1, 16), dim3(32, 8), 0, stream>>>(
        qkv + 524288, kt, inv + 128, 32, 4096, 4, 1048576L, 131072L, 256, 32);
    k_attn<<<512, 256, 0, stream>>>(qt, kt, vb, ot);
    k_gemm2<<<1024, 256, 0, stream>>>(wob, ot, bout, y);
}